// Round 2
// baseline (1040.523 us; speedup 1.0000x reference)
//
#include <hip/hip_runtime.h>
#include <hip/hip_bf16.h>

#define NNODES 20000
#define NEDGES 320000
#define ETOT   (NEDGES + NNODES)   // 340000, self-loops appended after edges
#define KPAD1  4448                // 4424 padded to /32
#define MPAD   20096               // 157*128
#define NCLS   151
#define EPRW   4808                // 4096 + 512 + 200
#define OUT_LAB_OFF  3020000L      // N*151
#define OUT_EPR_OFF  3040000L      // N*151 + N
#define NSLOPE 0.2f

typedef __attribute__((ext_vector_type(8))) short bf16x8;
typedef __attribute__((ext_vector_type(4))) float f32x4;

__device__ __forceinline__ short f2bf(float v) {
  union { __hip_bfloat16 b; short s; } u;
  u.b = __float2bfloat16(v);
  return u.s;
}

__device__ __forceinline__ void atomicMaxF(float* addr, float v) {
  if (v >= 0.f) atomicMax((int*)addr, __float_as_int(v));
  else          atomicMin((unsigned int*)addr, __float_as_uint(v));
}

__device__ __forceinline__ void gld16(const short* g, short* l) {
  __builtin_amdgcn_global_load_lds(
      (const __attribute__((address_space(1))) unsigned int*)g,
      (__attribute__((address_space(3))) unsigned int*)l, 16, 0, 0);
}

// ---------------------------------------------------------------------------
// build x (bf16, K-padded), plus obj_dists one-hot, labels, epr roi/emb2 parts
// one block (256 thr) per node. d_out is FLOAT32.
// ---------------------------------------------------------------------------
__global__ __launch_bounds__(256) void build_x_kernel(
    const float* __restrict__ roi, const float* __restrict__ box,
    const float* __restrict__ emb1, const float* __restrict__ emb2,
    const float* __restrict__ bw1, const float* __restrict__ bb1,
    const float* __restrict__ bw2, const float* __restrict__ bb2,
    const int* __restrict__ labels,
    short* __restrict__ x, float* __restrict__ dout) {
  const int n = blockIdx.x;
  const int tid = threadIdx.x;
  __shared__ float hid[32];
  __shared__ float bx[9];
  if (tid < 9) bx[tid] = box[n * 9 + tid];
  __syncthreads();
  if (tid < 32) {
    float a = bb1[tid];
#pragma unroll
    for (int i = 0; i < 9; ++i) a += bx[i] * bw1[i * 32 + tid];
    hid[tid] = a > 0.f ? a : 0.f;
  }
  __syncthreads();
  const long xrow = (long)n * KPAD1;
  if (tid < 128) {
    float a = bb2[tid];
#pragma unroll
    for (int i = 0; i < 32; ++i) a += hid[i] * bw2[i * 128 + tid];
    a = a > 0.f ? a : 0.f;
    x[xrow + 4296 + tid] = f2bf(a);      // pos MLP output (x cols 4296..4423)
  }
  if (tid >= 128 && tid < 152) x[xrow + 4424 + (tid - 128)] = 0;  // K pad
  const int lab = labels[n];
  float* epr = dout + OUT_EPR_OFF + (long)n * EPRW;
  for (int j = tid; j < 4096; j += 256) {
    const float v = roi[(long)n * 4096 + j];
    x[xrow + j] = f2bf(v);
    epr[j] = v;                           // exact f32 copy
  }
  for (int j = tid; j < 200; j += 256) {
    x[xrow + 4096 + j] = f2bf(emb1[lab * 200 + j]);
    epr[4608 + j]      = emb2[lab * 200 + j];
  }
  for (int j = tid; j < NCLS; j += 256)
    dout[(long)n * NCLS + j] = (j == lab) ? 1.f : 0.f;
  if (tid == 0) dout[OUT_LAB_OFF + n] = (float)lab;
}

// zero the M-pad rows of x and ef1 (rows 20000..20095)
__global__ void pad_zero_kernel(short* __restrict__ x, short* __restrict__ ef1) {
  const int t = blockIdx.x * 256 + threadIdx.x;
  if (t < 96 * KPAD1) x[(long)NNODES * KPAD1 + t] = 0;
  if (t < 96 * 512)   ef1[(long)NNODES * 512 + t] = 0;
}

// WT[n][kp] = (kp < K) ? W[kp][n] : 0   (f32 -> bf16)
__global__ void transpose_w_kernel(const float* __restrict__ W, short* __restrict__ WT,
                                   int K, int Kpad, int Ncols) {
  const long t = (long)blockIdx.x * 256 + threadIdx.x;
  if (t >= (long)Ncols * Kpad) return;
  const int nn = (int)(t / Kpad), kp = (int)(t % Kpad);
  WT[t] = f2bf(kp < K ? W[(long)kp * Ncols + nn] : 0.f);
}

// ---------------------------------------------------------------------------
// C[Mpad,Ncols] f32 = A[Mpad,Kpad] bf16 @ BT[Ncols,Kpad]^T bf16
// 128x128 tile, BK=32, 4 waves, global_load_lds width 16 (m97 structure)
// ---------------------------------------------------------------------------
__global__ __launch_bounds__(256) void gemm_bt(const short* __restrict__ A,
                                               const short* __restrict__ BT,
                                               float* __restrict__ C,
                                               int Kpad, int Ncols) {
  __shared__ short As[4096];   // [128 rows][32 k]
  __shared__ short Bs[4096];   // [128 cols][32 k]
  const int tid = threadIdx.x;
  const int lane = tid & 63;
  const int w = tid >> 6;
  const int wr = w >> 1, wc = w & 1;
  const long bm = (long)blockIdx.x * 128;
  const long bn = (long)blockIdx.y * 128;

  f32x4 acc[4][4] = {};

  const short* gA0 = A + (bm + w * 32 + (lane >> 2)) * (long)Kpad + (lane & 3) * 8;
  const short* gA1 = gA0 + 16L * Kpad;
  const short* gB0 = BT + (bn + w * 32 + (lane >> 2)) * (long)Kpad + (lane & 3) * 8;
  const short* gB1 = gB0 + 16L * Kpad;
  short* lA0 = &As[w * 1024];
  short* lA1 = &As[w * 1024 + 512];
  short* lB0 = &Bs[w * 1024];
  short* lB1 = &Bs[w * 1024 + 512];

  const int ar = (wr * 64 + (lane & 15)) * 32 + (lane >> 4) * 8;
  const int br = (wc * 64 + (lane & 15)) * 32 + (lane >> 4) * 8;

  for (int k0 = 0; k0 < Kpad; k0 += 32) {
    gld16(gA0, lA0); gld16(gA1, lA1);
    gld16(gB0, lB0); gld16(gB1, lB1);
    gA0 += 32; gA1 += 32; gB0 += 32; gB1 += 32;
    asm volatile("s_waitcnt vmcnt(0)" ::: "memory");
    __syncthreads();
    bf16x8 a[4], b[4];
#pragma unroll
    for (int mi = 0; mi < 4; ++mi) a[mi] = *(const bf16x8*)&As[ar + mi * 512];
#pragma unroll
    for (int ni = 0; ni < 4; ++ni) b[ni] = *(const bf16x8*)&Bs[br + ni * 512];
#pragma unroll
    for (int mi = 0; mi < 4; ++mi)
#pragma unroll
      for (int ni = 0; ni < 4; ++ni)
        acc[mi][ni] = __builtin_amdgcn_mfma_f32_16x16x32_bf16(a[mi], b[ni], acc[mi][ni], 0, 0, 0);
    __syncthreads();
  }

#pragma unroll
  for (int mi = 0; mi < 4; ++mi) {
#pragma unroll
    for (int ni = 0; ni < 4; ++ni) {
      const long row0 = bm + wr * 64 + mi * 16 + (lane >> 4) * 4;
      const long col  = bn + wc * 64 + ni * 16 + (lane & 15);
#pragma unroll
      for (int r = 0; r < 4; ++r)
        C[(row0 + r) * (long)Ncols + col] = acc[mi][ni][r];
    }
  }
}

// ---------------------------------------------------------------------------
// attention helper kernels
// ---------------------------------------------------------------------------
// als/ald for conv1: one 64-lane group per (node, head); C=64
__global__ __launch_bounds__(256) void alsd1_kernel(const float* __restrict__ h,
    const float* __restrict__ a_src, const float* __restrict__ a_dst,
    float* __restrict__ als, float* __restrict__ ald) {
  const int g = (blockIdx.x * 256 + threadIdx.x) >> 6;
  const int lane = threadIdx.x & 63;
  if (g >= NNODES * 8) return;
  const int node = g >> 3, hh = g & 7;
  const float v = h[(long)node * 512 + hh * 64 + lane];
  float s = v * a_src[hh * 64 + lane];
  float d = v * a_dst[hh * 64 + lane];
#pragma unroll
  for (int o = 32; o > 0; o >>= 1) { s += __shfl_xor(s, o); d += __shfl_xor(d, o); }
  if (lane == 0) { als[g] = s; ald[g] = d; }
}

// als/ald for conv2: one 64-lane group per node; C=512
__global__ __launch_bounds__(256) void alsd2_kernel(const float* __restrict__ h,
    const float* __restrict__ a_src, const float* __restrict__ a_dst,
    float* __restrict__ als, float* __restrict__ ald) {
  const int g = (blockIdx.x * 256 + threadIdx.x) >> 6;
  const int lane = threadIdx.x & 63;
  if (g >= NNODES) return;
  float s = 0.f, d = 0.f;
#pragma unroll
  for (int j = 0; j < 8; ++j) {
    const int c = j * 64 + lane;
    const float v = h[(long)g * 512 + c];
    s += v * a_src[c];
    d += v * a_dst[c];
  }
#pragma unroll
  for (int o = 32; o > 0; o >>= 1) { s += __shfl_xor(s, o); d += __shfl_xor(d, o); }
  if (lane == 0) { als[g] = s; ald[g] = d; }
}

__global__ void init_kernel(float* mx1, float* sm1, float* mx2, float* sm2, int* deg) {
  const int t = blockIdx.x * 256 + threadIdx.x;
  if (t < NNODES * 8) { mx1[t] = -1e30f; sm1[t] = 0.f; }
  if (t < NNODES)     { mx2[t] = -1e30f; sm2[t] = 0.f; deg[t] = 0; }
}

__global__ void deg_count_kernel(const int* __restrict__ ei, int* __restrict__ deg) {
  const int e = blockIdx.x * 256 + threadIdx.x;
  if (e >= ETOT) return;
  const int d = (e < NEDGES) ? ei[NEDGES + e] : (e - NEDGES);
  atomicAdd(&deg[d], 1);
}

// single-block exclusive scan over 20000 degrees -> off, cursor
__global__ __launch_bounds__(256) void scan_kernel(const int* __restrict__ deg,
                                                   int* __restrict__ off,
                                                   int* __restrict__ cur) {
  __shared__ int part[256];
  const int tid = threadIdx.x;
  const int chunk = (NNODES + 255) / 256;
  int start = tid * chunk;
  int end = start + chunk; if (end > NNODES) end = NNODES;
  int s = 0;
  for (int i = start; i < end; ++i) s += deg[i];
  part[tid] = s;
  __syncthreads();
  for (int d = 1; d < 256; d <<= 1) {
    const int v = (tid >= d) ? part[tid - d] : 0;
    __syncthreads();
    part[tid] += v;
    __syncthreads();
  }
  int base = part[tid] - s;   // exclusive base of this thread's chunk
  for (int i = start; i < end; ++i) { off[i] = base; cur[i] = base; base += deg[i]; }
}

__global__ void csr_fill_kernel(const int* __restrict__ ei, int* __restrict__ cur,
                                int* __restrict__ csrs, int* __restrict__ csre) {
  const int e = blockIdx.x * 256 + threadIdx.x;
  if (e >= ETOT) return;
  const int s = (e < NEDGES) ? ei[e] : (e - NEDGES);
  const int d = (e < NEDGES) ? ei[NEDGES + e] : (e - NEDGES);
  const int slot = atomicAdd(&cur[d], 1);
  csrs[slot] = s;
  csre[slot] = e;
}

__global__ void edge_logits_kernel(const int* __restrict__ ei, const float* __restrict__ als,
                                   const float* __restrict__ ald, float* __restrict__ wbuf,
                                   float* __restrict__ mx, int H) {
  const int e = blockIdx.x * 256 + threadIdx.x;
  if (e >= ETOT) return;
  const int s = (e < NEDGES) ? ei[e] : (e - NEDGES);
  const int d = (e < NEDGES) ? ei[NEDGES + e] : (e - NEDGES);
  for (int h = 0; h < H; ++h) {
    float l = als[s * H + h] + ald[d * H + h];
    l = l > 0.f ? l : NSLOPE * l;
    wbuf[(long)e * H + h] = l;
    atomicMaxF(&mx[d * H + h], l);
  }
}

__global__ void edge_expsum_kernel(const int* __restrict__ ei, float* __restrict__ wbuf,
                                   const float* __restrict__ mx, float* __restrict__ sm, int H) {
  const int e = blockIdx.x * 256 + threadIdx.x;
  if (e >= ETOT) return;
  const int d = (e < NEDGES) ? ei[NEDGES + e] : (e - NEDGES);
  for (int h = 0; h < H; ++h) {
    const float w = expf(wbuf[(long)e * H + h] - mx[d * H + h]);
    wbuf[(long)e * H + h] = w;
    atomicAdd(&sm[d * H + h], w);
  }
}

// conv1 gather: block per dst node, thread owns channels (tid, tid+256); 8 heads x 64
__global__ __launch_bounds__(256) void gather1_kernel(const int* __restrict__ off,
    const int* __restrict__ csrs, const int* __restrict__ csre,
    const float* __restrict__ wbuf, const float* __restrict__ sm,
    const float* __restrict__ h1, const float* __restrict__ bias,
    short* __restrict__ ef1) {
  const int dn = blockIdx.x;
  const int tid = threadIdx.x;
  const int c0 = tid, c1 = tid + 256;
  const int h0 = c0 >> 6, h1i = c1 >> 6;
  float acc0 = 0.f, acc1 = 0.f;
  const int beg = off[dn];
  const int end = (dn == NNODES - 1) ? ETOT : off[dn + 1];
  for (int i = beg; i < end; ++i) {
    const int s = csrs[i];
    const long e = csre[i];
    const float w0 = wbuf[e * 8 + h0];
    const float w1 = wbuf[e * 8 + h1i];
    const float* hr = h1 + (long)s * 512;
    acc0 += w0 * hr[c0];
    acc1 += w1 * hr[c1];
  }
  float r0 = acc0 / (sm[dn * 8 + h0]  + 1e-16f) + bias[c0];
  float r1 = acc1 / (sm[dn * 8 + h1i] + 1e-16f) + bias[c1];
  r0 = r0 > 0.f ? r0 : expm1f(r0);   // elu
  r1 = r1 > 0.f ? r1 : expm1f(r1);
  ef1[(long)dn * 512 + c0] = f2bf(r0);
  ef1[(long)dn * 512 + c1] = f2bf(r1);
}

// conv2 gather: H=1, writes obj_feats slice of edge_pre_rep directly (f32)
__global__ __launch_bounds__(256) void gather2_kernel(const int* __restrict__ off,
    const int* __restrict__ csrs, const int* __restrict__ csre,
    const float* __restrict__ wbuf, const float* __restrict__ sm,
    const float* __restrict__ h2, const float* __restrict__ bias,
    float* __restrict__ dout) {
  const int dn = blockIdx.x;
  const int tid = threadIdx.x;
  float acc0 = 0.f, acc1 = 0.f;
  const int beg = off[dn];
  const int end = (dn == NNODES - 1) ? ETOT : off[dn + 1];
  for (int i = beg; i < end; ++i) {
    const int s = csrs[i];
    const float w = wbuf[csre[i]];
    const float* hr = h2 + (long)s * 512;
    acc0 += w * hr[tid];
    acc1 += w * hr[tid + 256];
  }
  const float inv = 1.f / (sm[dn] + 1e-16f);
  float* epr = dout + OUT_EPR_OFF + (long)dn * EPRW + 4096;
  epr[tid]       = acc0 * inv + bias[tid];
  epr[tid + 256] = acc1 * inv + bias[tid + 256];
}

// ---------------------------------------------------------------------------
extern "C" void kernel_launch(void* const* d_in, const int* in_sizes, int n_in,
                              void* d_out, int out_size, void* d_ws, size_t ws_size,
                              hipStream_t stream) {
  const float* roi  = (const float*)d_in[0];
  const float* box  = (const float*)d_in[1];
  const float* emb1 = (const float*)d_in[2];
  const float* emb2 = (const float*)d_in[3];
  const float* bw1  = (const float*)d_in[4];
  const float* bb1  = (const float*)d_in[5];
  const float* bw2  = (const float*)d_in[6];
  const float* bb2  = (const float*)d_in[7];
  const float* W1   = (const float*)d_in[8];
  const float* as1  = (const float*)d_in[9];
  const float* ad1  = (const float*)d_in[10];
  const float* b1   = (const float*)d_in[11];
  const float* W2   = (const float*)d_in[12];
  const float* as2  = (const float*)d_in[13];
  const float* ad2  = (const float*)d_in[14];
  const float* b2   = (const float*)d_in[15];
  const int* labels = (const int*)d_in[16];
  const int* ei     = (const int*)d_in[17];
  float* dout = (float*)d_out;

  char* wsb = (char*)d_ws;
  size_t o = 0;
  auto alloc = [&](size_t bytes) -> void* {
    void* p = wsb + o;
    o += (bytes + 255) & ~(size_t)255;
    return p;
  };
  short* x    = (short*)alloc((size_t)MPAD * KPAD1 * 2);   // bf16 [MPAD][4448]
  short* w1t  = (short*)alloc((size_t)512 * KPAD1 * 2);    // bf16 [512][4448]
  float* h1   = (float*)alloc((size_t)MPAD * 512 * 4);
  short* ef1  = (short*)alloc((size_t)MPAD * 512 * 2);     // bf16 [MPAD][512]
  short* w2t  = (short*)alloc((size_t)512 * 512 * 2);
  float* h2   = (float*)alloc((size_t)MPAD * 512 * 4);
  float* als1 = (float*)alloc((size_t)NNODES * 8 * 4);
  float* ald1 = (float*)alloc((size_t)NNODES * 8 * 4);
  float* mx1  = (float*)alloc((size_t)NNODES * 8 * 4);
  float* sm1  = (float*)alloc((size_t)NNODES * 8 * 4);
  float* wb1  = (float*)alloc((size_t)ETOT * 8 * 4);
  float* als2 = (float*)alloc((size_t)NNODES * 4);
  float* ald2 = (float*)alloc((size_t)NNODES * 4);
  float* mx2  = (float*)alloc((size_t)NNODES * 4);
  float* sm2  = (float*)alloc((size_t)NNODES * 4);
  float* wb2  = (float*)alloc((size_t)ETOT * 4);
  int*   deg  = (int*)alloc((size_t)NNODES * 4);
  int*   offs = (int*)alloc((size_t)NNODES * 4);
  int*   cur  = (int*)alloc((size_t)NNODES * 4);
  int*   csrs = (int*)alloc((size_t)ETOT * 4);
  int*   csre = (int*)alloc((size_t)ETOT * 4);

  const int EB = (ETOT + 255) / 256;   // 1329

  hipLaunchKernelGGL(init_kernel, dim3((NNODES * 8 + 255) / 256), dim3(256), 0, stream,
                     mx1, sm1, mx2, sm2, deg);
  hipLaunchKernelGGL(build_x_kernel, dim3(NNODES), dim3(256), 0, stream,
                     roi, box, emb1, emb2, bw1, bb1, bw2, bb2, labels, x, dout);
  hipLaunchKernelGGL(pad_zero_kernel, dim3((96 * KPAD1 + 255) / 256), dim3(256), 0, stream,
                     x, ef1);
  hipLaunchKernelGGL(transpose_w_kernel, dim3((512 * KPAD1 + 255) / 256), dim3(256), 0, stream,
                     W1, w1t, 4424, KPAD1, 512);
  hipLaunchKernelGGL(transpose_w_kernel, dim3((512 * 512 + 255) / 256), dim3(256), 0, stream,
                     W2, w2t, 512, 512, 512);
  // CSR build
  hipLaunchKernelGGL(deg_count_kernel, dim3(EB), dim3(256), 0, stream, ei, deg);
  hipLaunchKernelGGL(scan_kernel, dim3(1), dim3(256), 0, stream, deg, offs, cur);
  hipLaunchKernelGGL(csr_fill_kernel, dim3(EB), dim3(256), 0, stream, ei, cur, csrs, csre);
  // conv1
  hipLaunchKernelGGL(gemm_bt, dim3(MPAD / 128, 4), dim3(256), 0, stream,
                     x, w1t, h1, KPAD1, 512);
  hipLaunchKernelGGL(alsd1_kernel, dim3(NNODES * 8 * 64 / 256), dim3(256), 0, stream,
                     h1, as1, ad1, als1, ald1);
  hipLaunchKernelGGL(edge_logits_kernel, dim3(EB), dim3(256), 0, stream,
                     ei, als1, ald1, wb1, mx1, 8);
  hipLaunchKernelGGL(edge_expsum_kernel, dim3(EB), dim3(256), 0, stream,
                     ei, wb1, mx1, sm1, 8);
  hipLaunchKernelGGL(gather1_kernel, dim3(NNODES), dim3(256), 0, stream,
                     offs, csrs, csre, wb1, sm1, h1, b1, ef1);
  // conv2
  hipLaunchKernelGGL(gemm_bt, dim3(MPAD / 128, 4), dim3(256), 0, stream,
                     ef1, w2t, h2, 512, 512);
  hipLaunchKernelGGL(alsd2_kernel, dim3(NNODES * 64 / 256), dim3(256), 0, stream,
                     h2, as2, ad2, als2, ald2);
  hipLaunchKernelGGL(edge_logits_kernel, dim3(EB), dim3(256), 0, stream,
                     ei, als2, ald2, wb2, mx2, 1);
  hipLaunchKernelGGL(edge_expsum_kernel, dim3(EB), dim3(256), 0, stream,
                     ei, wb2, mx2, sm2, 1);
  hipLaunchKernelGGL(gather2_kernel, dim3(NNODES), dim3(256), 0, stream,
                     offs, csrs, csre, wb2, sm2, h2, b2, dout);
}

// Round 3
// 755.264 us; speedup vs baseline: 1.3777x; 1.3777x over previous
//
#include <hip/hip_runtime.h>
#include <hip/hip_bf16.h>

#define NNODES 20000
#define NEDGES 320000
#define ETOT   (NEDGES + NNODES)   // 340000, self-loops appended after edges
#define KPAD1  4448                // 4424 padded to /32
#define MPAD   20096               // 157*128
#define NCLS   151
#define EPRW   4808                // 4096 + 512 + 200
#define OUT_LAB_OFF  3020000L      // N*151
#define OUT_EPR_OFF  3040000L      // N*151 + N
#define NSLOPE 0.2f

typedef __attribute__((ext_vector_type(8))) short bf16x8;
typedef __attribute__((ext_vector_type(4))) float f32x4;

__device__ __forceinline__ short f2bf(float v) {
  union { __hip_bfloat16 b; short s; } u;
  u.b = __float2bfloat16(v);
  return u.s;
}

__device__ __forceinline__ void gld16(const short* g, short* l) {
  __builtin_amdgcn_global_load_lds(
      (const __attribute__((address_space(1))) unsigned int*)g,
      (__attribute__((address_space(3))) unsigned int*)l, 16, 0, 0);
}

// ---------------------------------------------------------------------------
// build x (bf16, K-padded), plus obj_dists one-hot, labels, epr roi/emb2 parts
// one block (256 thr) per node. d_out is FLOAT32. Vectorized float4/short4.
// ---------------------------------------------------------------------------
__global__ __launch_bounds__(256) void build_x_kernel(
    const float* __restrict__ roi, const float* __restrict__ box,
    const float* __restrict__ emb1, const float* __restrict__ emb2,
    const float* __restrict__ bw1, const float* __restrict__ bb1,
    const float* __restrict__ bw2, const float* __restrict__ bb2,
    const int* __restrict__ labels,
    short* __restrict__ x, float* __restrict__ dout) {
  const int n = blockIdx.x;
  const int tid = threadIdx.x;
  __shared__ float hid[32];
  __shared__ float bx[9];
  if (tid < 9) bx[tid] = box[n * 9 + tid];
  __syncthreads();
  if (tid < 32) {
    float a = bb1[tid];
#pragma unroll
    for (int i = 0; i < 9; ++i) a += bx[i] * bw1[i * 32 + tid];
    hid[tid] = a > 0.f ? a : 0.f;
  }
  __syncthreads();
  const long xrow = (long)n * KPAD1;
  if (tid < 128) {
    float a = bb2[tid];
#pragma unroll
    for (int i = 0; i < 32; ++i) a += hid[i] * bw2[i * 128 + tid];
    a = a > 0.f ? a : 0.f;
    x[xrow + 4296 + tid] = f2bf(a);      // pos MLP output (x cols 4296..4423)
  }
  if (tid >= 128 && tid < 152) x[xrow + 4424 + (tid - 128)] = 0;  // K pad
  const int lab = labels[n];
  float* epr = dout + OUT_EPR_OFF + (long)n * EPRW;
#pragma unroll
  for (int j = tid * 4; j < 4096; j += 1024) {
    const float4 v = *(const float4*)&roi[(long)n * 4096 + j];
    *(float4*)&epr[j] = v;               // exact f32 copy
    short4 b;
    b.x = f2bf(v.x); b.y = f2bf(v.y); b.z = f2bf(v.z); b.w = f2bf(v.w);
    *(short4*)&x[xrow + j] = b;
  }
  if (tid < 50) {
    const int j = tid * 4;
    const float4 e1 = *(const float4*)&emb1[lab * 200 + j];
    short4 b;
    b.x = f2bf(e1.x); b.y = f2bf(e1.y); b.z = f2bf(e1.z); b.w = f2bf(e1.w);
    *(short4*)&x[xrow + 4096 + j] = b;
    *(float4*)&epr[4608 + j] = *(const float4*)&emb2[lab * 200 + j];
  }
  for (int j = tid; j < NCLS; j += 256)
    dout[(long)n * NCLS + j] = (j == lab) ? 1.f : 0.f;
  if (tid == 0) dout[OUT_LAB_OFF + n] = (float)lab;
}

// zero the M-pad rows of x and ef1 (rows 20000..20095), and deg
__global__ void pad_zero_kernel(short* __restrict__ x, short* __restrict__ ef1,
                                int* __restrict__ deg) {
  const int t = blockIdx.x * 256 + threadIdx.x;
  if (t < 96 * KPAD1) x[(long)NNODES * KPAD1 + t] = 0;
  if (t < 96 * 512)   ef1[(long)NNODES * 512 + t] = 0;
  if (t < NNODES)     deg[t] = 0;
}

// LDS-tiled transpose: WT[n][kp] = (kp < K) ? W[kp][n] : 0  (f32 -> bf16)
// block (32,8), grid (Ncols/32, Kpad/32)
__global__ __launch_bounds__(256) void transpose_w_kernel(
    const float* __restrict__ W, short* __restrict__ WT, int K, int Kpad, int Ncols) {
  __shared__ float tile[32][33];
  const int n0 = blockIdx.x * 32;
  const int k0 = blockIdx.y * 32;
  const int tx = threadIdx.x;   // 0..31
  const int ty = threadIdx.y;   // 0..7
#pragma unroll
  for (int i = ty; i < 32; i += 8) {
    const int k = k0 + i;
    tile[i][tx] = (k < K) ? W[(long)k * Ncols + (n0 + tx)] : 0.f;
  }
  __syncthreads();
#pragma unroll
  for (int i = ty; i < 32; i += 8) {
    WT[(long)(n0 + i) * Kpad + (k0 + tx)] = f2bf(tile[tx][i]);
  }
}

// ---------------------------------------------------------------------------
// C[Mpad,Ncols] f32 = A[Mpad,Kpad] bf16 @ BT[Ncols,Kpad]^T bf16
// 128x128 tile, BK=32, 4 waves, global_load_lds width 16 (m97 structure)
// ---------------------------------------------------------------------------
__global__ __launch_bounds__(256) void gemm_bt(const short* __restrict__ A,
                                               const short* __restrict__ BT,
                                               float* __restrict__ C,
                                               int Kpad, int Ncols) {
  __shared__ short As[4096];   // [128 rows][32 k]
  __shared__ short Bs[4096];   // [128 cols][32 k]
  const int tid = threadIdx.x;
  const int lane = tid & 63;
  const int w = tid >> 6;
  const int wr = w >> 1, wc = w & 1;
  const long bm = (long)blockIdx.x * 128;
  const long bn = (long)blockIdx.y * 128;

  f32x4 acc[4][4] = {};

  const short* gA0 = A + (bm + w * 32 + (lane >> 2)) * (long)Kpad + (lane & 3) * 8;
  const short* gA1 = gA0 + 16L * Kpad;
  const short* gB0 = BT + (bn + w * 32 + (lane >> 2)) * (long)Kpad + (lane & 3) * 8;
  const short* gB1 = gB0 + 16L * Kpad;
  short* lA0 = &As[w * 1024];
  short* lA1 = &As[w * 1024 + 512];
  short* lB0 = &Bs[w * 1024];
  short* lB1 = &Bs[w * 1024 + 512];

  const int ar = (wr * 64 + (lane & 15)) * 32 + (lane >> 4) * 8;
  const int br = (wc * 64 + (lane & 15)) * 32 + (lane >> 4) * 8;

  for (int k0 = 0; k0 < Kpad; k0 += 32) {
    gld16(gA0, lA0); gld16(gA1, lA1);
    gld16(gB0, lB0); gld16(gB1, lB1);
    gA0 += 32; gA1 += 32; gB0 += 32; gB1 += 32;
    asm volatile("s_waitcnt vmcnt(0)" ::: "memory");
    __syncthreads();
    bf16x8 a[4], b[4];
#pragma unroll
    for (int mi = 0; mi < 4; ++mi) a[mi] = *(const bf16x8*)&As[ar + mi * 512];
#pragma unroll
    for (int ni = 0; ni < 4; ++ni) b[ni] = *(const bf16x8*)&Bs[br + ni * 512];
#pragma unroll
    for (int mi = 0; mi < 4; ++mi)
#pragma unroll
      for (int ni = 0; ni < 4; ++ni)
        acc[mi][ni] = __builtin_amdgcn_mfma_f32_16x16x32_bf16(a[mi], b[ni], acc[mi][ni], 0, 0, 0);
    __syncthreads();
  }

#pragma unroll
  for (int mi = 0; mi < 4; ++mi) {
#pragma unroll
    for (int ni = 0; ni < 4; ++ni) {
      const long row0 = bm + wr * 64 + mi * 16 + (lane >> 4) * 4;
      const long col  = bn + wc * 64 + ni * 16 + (lane & 15);
#pragma unroll
      for (int r = 0; r < 4; ++r)
        C[(row0 + r) * (long)Ncols + col] = acc[mi][ni][r];
    }
  }
}

// ---------------------------------------------------------------------------
// attention helper kernels
// ---------------------------------------------------------------------------
// als/ald for conv1: one 64-lane group per (node, head); C=64
__global__ __launch_bounds__(256) void alsd1_kernel(const float* __restrict__ h,
    const float* __restrict__ a_src, const float* __restrict__ a_dst,
    float* __restrict__ als, float* __restrict__ ald) {
  const int g = (blockIdx.x * 256 + threadIdx.x) >> 6;
  const int lane = threadIdx.x & 63;
  if (g >= NNODES * 8) return;
  const int node = g >> 3, hh = g & 7;
  const float v = h[(long)node * 512 + hh * 64 + lane];
  float s = v * a_src[hh * 64 + lane];
  float d = v * a_dst[hh * 64 + lane];
#pragma unroll
  for (int o = 32; o > 0; o >>= 1) { s += __shfl_xor(s, o); d += __shfl_xor(d, o); }
  if (lane == 0) { als[g] = s; ald[g] = d; }
}

// als/ald for conv2: one 64-lane group per node; C=512
__global__ __launch_bounds__(256) void alsd2_kernel(const float* __restrict__ h,
    const float* __restrict__ a_src, const float* __restrict__ a_dst,
    float* __restrict__ als, float* __restrict__ ald) {
  const int g = (blockIdx.x * 256 + threadIdx.x) >> 6;
  const int lane = threadIdx.x & 63;
  if (g >= NNODES) return;
  float s = 0.f, d = 0.f;
#pragma unroll
  for (int j = 0; j < 8; ++j) {
    const int c = j * 64 + lane;
    const float v = h[(long)g * 512 + c];
    s += v * a_src[c];
    d += v * a_dst[c];
  }
#pragma unroll
  for (int o = 32; o > 0; o >>= 1) { s += __shfl_xor(s, o); d += __shfl_xor(d, o); }
  if (lane == 0) { als[g] = s; ald[g] = d; }
}

__global__ void deg_count_kernel(const int* __restrict__ ei, int* __restrict__ deg) {
  const int e = blockIdx.x * 256 + threadIdx.x;
  if (e >= ETOT) return;
  const int d = (e < NEDGES) ? ei[NEDGES + e] : (e - NEDGES);
  atomicAdd(&deg[d], 1);
}

// single-block exclusive scan over 20000 degrees -> off, cursor
__global__ __launch_bounds__(256) void scan_kernel(const int* __restrict__ deg,
                                                   int* __restrict__ off,
                                                   int* __restrict__ cur) {
  __shared__ int part[256];
  const int tid = threadIdx.x;
  const int chunk = (NNODES + 255) / 256;
  int start = tid * chunk;
  int end = start + chunk; if (end > NNODES) end = NNODES;
  int s = 0;
  for (int i = start; i < end; ++i) s += deg[i];
  part[tid] = s;
  __syncthreads();
  for (int d = 1; d < 256; d <<= 1) {
    const int v = (tid >= d) ? part[tid - d] : 0;
    __syncthreads();
    part[tid] += v;
    __syncthreads();
  }
  int base = part[tid] - s;   // exclusive base of this thread's chunk
  for (int i = start; i < end; ++i) { off[i] = base; cur[i] = base; base += deg[i]; }
}

__global__ void csr_fill_kernel(const int* __restrict__ ei, int* __restrict__ cur,
                                int* __restrict__ csrs) {
  const int e = blockIdx.x * 256 + threadIdx.x;
  if (e >= ETOT) return;
  const int s = (e < NEDGES) ? ei[e] : (e - NEDGES);
  const int d = (e < NEDGES) ? ei[NEDGES + e] : (e - NEDGES);
  csrs[atomicAdd(&cur[d], 1)] = s;
}

// ---------------------------------------------------------------------------
// fused per-node softmax + gather (conv1): block per dst node,
// thread owns channels (2*tid, 2*tid+1); head = (2*tid)>>6. No atomics.
// ---------------------------------------------------------------------------
__global__ __launch_bounds__(256) void gather1_kernel(const int* __restrict__ off,
    const int* __restrict__ csrs,
    const float* __restrict__ als, const float* __restrict__ ald,
    const float* __restrict__ h1, const float* __restrict__ bias,
    short* __restrict__ ef1) {
  const int dn = blockIdx.x;
  const int tid = threadIdx.x;
  const int c0 = tid * 2;
  const int h = c0 >> 6;
  const int beg = off[dn];
  const int end = (dn == NNODES - 1) ? ETOT : off[dn + 1];
  const float ad = ald[dn * 8 + h];
  float m = -1e30f;
  for (int i = beg; i < end; ++i) {
    float l = als[csrs[i] * 8 + h] + ad;
    l = l > 0.f ? l : NSLOPE * l;
    m = fmaxf(m, l);
  }
  float sum = 0.f, a0 = 0.f, a1 = 0.f;
  for (int i = beg; i < end; ++i) {
    const int s = csrs[i];
    float l = als[s * 8 + h] + ad;
    l = l > 0.f ? l : NSLOPE * l;
    const float wgt = expf(l - m);
    sum += wgt;
    const float2 hv = *(const float2*)&h1[(long)s * 512 + c0];
    a0 += wgt * hv.x;
    a1 += wgt * hv.y;
  }
  const float inv = 1.f / (sum + 1e-16f);
  float r0 = a0 * inv + bias[c0];
  float r1 = a1 * inv + bias[c0 + 1];
  r0 = r0 > 0.f ? r0 : expm1f(r0);   // elu
  r1 = r1 > 0.f ? r1 : expm1f(r1);
  ef1[(long)dn * 512 + c0]     = f2bf(r0);
  ef1[(long)dn * 512 + c0 + 1] = f2bf(r1);
}

// fused per-node softmax + gather (conv2, H=1): writes obj_feats slice (f32)
__global__ __launch_bounds__(256) void gather2_kernel(const int* __restrict__ off,
    const int* __restrict__ csrs,
    const float* __restrict__ als, const float* __restrict__ ald,
    const float* __restrict__ h2, const float* __restrict__ bias,
    float* __restrict__ dout) {
  const int dn = blockIdx.x;
  const int tid = threadIdx.x;
  const int c0 = tid * 2;
  const int beg = off[dn];
  const int end = (dn == NNODES - 1) ? ETOT : off[dn + 1];
  const float ad = ald[dn];
  float m = -1e30f;
  for (int i = beg; i < end; ++i) {
    float l = als[csrs[i]] + ad;
    l = l > 0.f ? l : NSLOPE * l;
    m = fmaxf(m, l);
  }
  float sum = 0.f, a0 = 0.f, a1 = 0.f;
  for (int i = beg; i < end; ++i) {
    const int s = csrs[i];
    float l = als[s] + ad;
    l = l > 0.f ? l : NSLOPE * l;
    const float wgt = expf(l - m);
    sum += wgt;
    const float2 hv = *(const float2*)&h2[(long)s * 512 + c0];
    a0 += wgt * hv.x;
    a1 += wgt * hv.y;
  }
  const float inv = 1.f / (sum + 1e-16f);
  float* epr = dout + OUT_EPR_OFF + (long)dn * EPRW + 4096;
  epr[c0]     = a0 * inv + bias[c0];
  epr[c0 + 1] = a1 * inv + bias[c0 + 1];
}

// ---------------------------------------------------------------------------
extern "C" void kernel_launch(void* const* d_in, const int* in_sizes, int n_in,
                              void* d_out, int out_size, void* d_ws, size_t ws_size,
                              hipStream_t stream) {
  const float* roi  = (const float*)d_in[0];
  const float* box  = (const float*)d_in[1];
  const float* emb1 = (const float*)d_in[2];
  const float* emb2 = (const float*)d_in[3];
  const float* bw1  = (const float*)d_in[4];
  const float* bb1  = (const float*)d_in[5];
  const float* bw2  = (const float*)d_in[6];
  const float* bb2  = (const float*)d_in[7];
  const float* W1   = (const float*)d_in[8];
  const float* as1  = (const float*)d_in[9];
  const float* ad1  = (const float*)d_in[10];
  const float* b1   = (const float*)d_in[11];
  const float* W2   = (const float*)d_in[12];
  const float* as2  = (const float*)d_in[13];
  const float* ad2  = (const float*)d_in[14];
  const float* b2   = (const float*)d_in[15];
  const int* labels = (const int*)d_in[16];
  const int* ei     = (const int*)d_in[17];
  float* dout = (float*)d_out;

  char* wsb = (char*)d_ws;
  size_t o = 0;
  auto alloc = [&](size_t bytes) -> void* {
    void* p = wsb + o;
    o += (bytes + 255) & ~(size_t)255;
    return p;
  };
  short* x    = (short*)alloc((size_t)MPAD * KPAD1 * 2);   // bf16 [MPAD][4448]
  short* w1t  = (short*)alloc((size_t)512 * KPAD1 * 2);    // bf16 [512][4448]
  float* h1   = (float*)alloc((size_t)MPAD * 512 * 4);
  short* ef1  = (short*)alloc((size_t)MPAD * 512 * 2);     // bf16 [MPAD][512]
  short* w2t  = (short*)alloc((size_t)512 * 512 * 2);
  float* h2   = (float*)alloc((size_t)MPAD * 512 * 4);
  float* als1 = (float*)alloc((size_t)NNODES * 8 * 4);
  float* ald1 = (float*)alloc((size_t)NNODES * 8 * 4);
  float* als2 = (float*)alloc((size_t)NNODES * 4);
  float* ald2 = (float*)alloc((size_t)NNODES * 4);
  int*   deg  = (int*)alloc((size_t)NNODES * 4);
  int*   offs = (int*)alloc((size_t)NNODES * 4);
  int*   cur  = (int*)alloc((size_t)NNODES * 4);
  int*   csrs = (int*)alloc((size_t)ETOT * 4);

  const int EB = (ETOT + 255) / 256;   // 1329

  hipLaunchKernelGGL(build_x_kernel, dim3(NNODES), dim3(256), 0, stream,
                     roi, box, emb1, emb2, bw1, bb1, bw2, bb2, labels, x, dout);
  hipLaunchKernelGGL(pad_zero_kernel, dim3((96 * KPAD1 + 255) / 256), dim3(256), 0, stream,
                     x, ef1, deg);
  hipLaunchKernelGGL(transpose_w_kernel, dim3(512 / 32, KPAD1 / 32), dim3(32, 8), 0, stream,
                     W1, w1t, 4424, KPAD1, 512);
  hipLaunchKernelGGL(transpose_w_kernel, dim3(512 / 32, 512 / 32), dim3(32, 8), 0, stream,
                     W2, w2t, 512, 512, 512);
  // CSR build
  hipLaunchKernelGGL(deg_count_kernel, dim3(EB), dim3(256), 0, stream, ei, deg);
  hipLaunchKernelGGL(scan_kernel, dim3(1), dim3(256), 0, stream, deg, offs, cur);
  hipLaunchKernelGGL(csr_fill_kernel, dim3(EB), dim3(256), 0, stream, ei, cur, csrs);
  // conv1
  hipLaunchKernelGGL(gemm_bt, dim3(MPAD / 128, 4), dim3(256), 0, stream,
                     x, w1t, h1, KPAD1, 512);
  hipLaunchKernelGGL(alsd1_kernel, dim3(NNODES * 8 * 64 / 256), dim3(256), 0, stream,
                     h1, as1, ad1, als1, ald1);
  hipLaunchKernelGGL(gather1_kernel, dim3(NNODES), dim3(256), 0, stream,
                     offs, csrs, als1, ald1, h1, b1, ef1);
  // conv2
  hipLaunchKernelGGL(gemm_bt, dim3(MPAD / 128, 4), dim3(256), 0, stream,
                     ef1, w2t, h2, 512, 512);
  hipLaunchKernelGGL(alsd2_kernel, dim3(NNODES * 64 / 256), dim3(256), 0, stream,
                     h2, as2, ad2, als2, ald2);
  hipLaunchKernelGGL(gather2_kernel, dim3(NNODES), dim3(256), 0, stream,
                     offs, csrs, als2, ald2, h2, b2, dout);
}

// Round 4
// 598.746 us; speedup vs baseline: 1.7378x; 1.2614x over previous
//
#include <hip/hip_runtime.h>
#include <hip/hip_bf16.h>

#define NNODES 20000
#define NEDGES 320000
#define ETOT   (NEDGES + NNODES)   // 340000, self-loops appended after edges
#define KPAD1  4448                // 4424 padded to /32
#define MPAD   20096               // 157*128
#define NCLS   151
#define EPRW   4808                // 4096 + 512 + 200
#define OUT_LAB_OFF  3020000L      // N*151
#define OUT_EPR_OFF  3040000L      // N*151 + N
#define NSLOPE 0.2f

typedef __attribute__((ext_vector_type(8))) short bf16x8;
typedef __attribute__((ext_vector_type(4))) float f32x4;

__device__ __forceinline__ short f2bf(float v) {
  union { __hip_bfloat16 b; short s; } u;
  u.b = __float2bfloat16(v);
  return u.s;
}

__device__ __forceinline__ float bf2f(short s) {
  union { float f; unsigned u; } x;
  x.u = ((unsigned)(unsigned short)s) << 16;
  return x.f;
}

__device__ __forceinline__ void gld16(const short* g, short* l) {
  __builtin_amdgcn_global_load_lds(
      (const __attribute__((address_space(1))) unsigned int*)g,
      (__attribute__((address_space(3))) unsigned int*)l, 16, 0, 0);
}

// ---------------------------------------------------------------------------
// build x (bf16, K-padded), plus obj_dists one-hot, labels, epr roi/emb2 parts
// one block (256 thr) per node. d_out is FLOAT32. Vectorized float4/short4.
// ---------------------------------------------------------------------------
__global__ __launch_bounds__(256) void build_x_kernel(
    const float* __restrict__ roi, const float* __restrict__ box,
    const float* __restrict__ emb1, const float* __restrict__ emb2,
    const float* __restrict__ bw1, const float* __restrict__ bb1,
    const float* __restrict__ bw2, const float* __restrict__ bb2,
    const int* __restrict__ labels,
    short* __restrict__ x, float* __restrict__ dout) {
  const int n = blockIdx.x;
  const int tid = threadIdx.x;
  __shared__ float hid[32];
  __shared__ float bx[9];
  if (tid < 9) bx[tid] = box[n * 9 + tid];
  __syncthreads();
  if (tid < 32) {
    float a = bb1[tid];
#pragma unroll
    for (int i = 0; i < 9; ++i) a += bx[i] * bw1[i * 32 + tid];
    hid[tid] = a > 0.f ? a : 0.f;
  }
  __syncthreads();
  const long xrow = (long)n * KPAD1;
  if (tid < 128) {
    float a = bb2[tid];
#pragma unroll
    for (int i = 0; i < 32; ++i) a += hid[i] * bw2[i * 128 + tid];
    a = a > 0.f ? a : 0.f;
    x[xrow + 4296 + tid] = f2bf(a);      // pos MLP output (x cols 4296..4423)
  }
  if (tid >= 128 && tid < 152) x[xrow + 4424 + (tid - 128)] = 0;  // K pad
  const int lab = labels[n];
  float* epr = dout + OUT_EPR_OFF + (long)n * EPRW;
#pragma unroll
  for (int j = tid * 4; j < 4096; j += 1024) {
    const float4 v = *(const float4*)&roi[(long)n * 4096 + j];
    *(float4*)&epr[j] = v;               // exact f32 copy
    short4 b;
    b.x = f2bf(v.x); b.y = f2bf(v.y); b.z = f2bf(v.z); b.w = f2bf(v.w);
    *(short4*)&x[xrow + j] = b;
  }
  if (tid < 50) {
    const int j = tid * 4;
    const float4 e1 = *(const float4*)&emb1[lab * 200 + j];
    short4 b;
    b.x = f2bf(e1.x); b.y = f2bf(e1.y); b.z = f2bf(e1.z); b.w = f2bf(e1.w);
    *(short4*)&x[xrow + 4096 + j] = b;
    *(float4*)&epr[4608 + j] = *(const float4*)&emb2[lab * 200 + j];
  }
  for (int j = tid; j < NCLS; j += 256)
    dout[(long)n * NCLS + j] = (j == lab) ? 1.f : 0.f;
  if (tid == 0) dout[OUT_LAB_OFF + n] = (float)lab;
}

// zero the M-pad rows of x and ef1 (rows 20000..20095), and deg
__global__ void pad_zero_kernel(short* __restrict__ x, short* __restrict__ ef1,
                                int* __restrict__ deg) {
  const int t = blockIdx.x * 256 + threadIdx.x;
  if (t < 96 * KPAD1) x[(long)NNODES * KPAD1 + t] = 0;
  if (t < 96 * 512)   ef1[(long)NNODES * 512 + t] = 0;
  if (t < NNODES)     deg[t] = 0;
}

// LDS-tiled transpose: WT[n][kp] = (kp < K) ? W[kp][n] : 0  (f32 -> bf16)
// block (32,8), grid (Ncols/32, Kpad/32)
__global__ __launch_bounds__(256) void transpose_w_kernel(
    const float* __restrict__ W, short* __restrict__ WT, int K, int Kpad, int Ncols) {
  __shared__ float tile[32][33];
  const int n0 = blockIdx.x * 32;
  const int k0 = blockIdx.y * 32;
  const int tx = threadIdx.x;   // 0..31
  const int ty = threadIdx.y;   // 0..7
#pragma unroll
  for (int i = ty; i < 32; i += 8) {
    const int k = k0 + i;
    tile[i][tx] = (k < K) ? W[(long)k * Ncols + (n0 + tx)] : 0.f;
  }
  __syncthreads();
#pragma unroll
  for (int i = ty; i < 32; i += 8) {
    WT[(long)(n0 + i) * Kpad + (k0 + tx)] = f2bf(tile[tx][i]);
  }
}

// ---------------------------------------------------------------------------
// C[Mpad,Ncols] bf16 = A[Mpad,Kpad] bf16 @ BT[Ncols,Kpad]^T bf16
// 128x128 tile, BK=32, 4 waves, global_load_lds width 16 (m97 structure)
// ---------------------------------------------------------------------------
__global__ __launch_bounds__(256) void gemm_bt(const short* __restrict__ A,
                                               const short* __restrict__ BT,
                                               short* __restrict__ C,
                                               int Kpad, int Ncols) {
  __shared__ short As[4096];   // [128 rows][32 k]
  __shared__ short Bs[4096];   // [128 cols][32 k]
  const int tid = threadIdx.x;
  const int lane = tid & 63;
  const int w = tid >> 6;
  const int wr = w >> 1, wc = w & 1;
  const long bm = (long)blockIdx.x * 128;
  const long bn = (long)blockIdx.y * 128;

  f32x4 acc[4][4] = {};

  const short* gA0 = A + (bm + w * 32 + (lane >> 2)) * (long)Kpad + (lane & 3) * 8;
  const short* gA1 = gA0 + 16L * Kpad;
  const short* gB0 = BT + (bn + w * 32 + (lane >> 2)) * (long)Kpad + (lane & 3) * 8;
  const short* gB1 = gB0 + 16L * Kpad;
  short* lA0 = &As[w * 1024];
  short* lA1 = &As[w * 1024 + 512];
  short* lB0 = &Bs[w * 1024];
  short* lB1 = &Bs[w * 1024 + 512];

  const int ar = (wr * 64 + (lane & 15)) * 32 + (lane >> 4) * 8;
  const int br = (wc * 64 + (lane & 15)) * 32 + (lane >> 4) * 8;

  for (int k0 = 0; k0 < Kpad; k0 += 32) {
    gld16(gA0, lA0); gld16(gA1, lA1);
    gld16(gB0, lB0); gld16(gB1, lB1);
    gA0 += 32; gA1 += 32; gB0 += 32; gB1 += 32;
    asm volatile("s_waitcnt vmcnt(0)" ::: "memory");
    __syncthreads();
    bf16x8 a[4], b[4];
#pragma unroll
    for (int mi = 0; mi < 4; ++mi) a[mi] = *(const bf16x8*)&As[ar + mi * 512];
#pragma unroll
    for (int ni = 0; ni < 4; ++ni) b[ni] = *(const bf16x8*)&Bs[br + ni * 512];
#pragma unroll
    for (int mi = 0; mi < 4; ++mi)
#pragma unroll
      for (int ni = 0; ni < 4; ++ni)
        acc[mi][ni] = __builtin_amdgcn_mfma_f32_16x16x32_bf16(a[mi], b[ni], acc[mi][ni], 0, 0, 0);
    __syncthreads();
  }

#pragma unroll
  for (int mi = 0; mi < 4; ++mi) {
#pragma unroll
    for (int ni = 0; ni < 4; ++ni) {
      const long row0 = bm + wr * 64 + mi * 16 + (lane >> 4) * 4;
      const long col  = bn + wc * 64 + ni * 16 + (lane & 15);
#pragma unroll
      for (int r = 0; r < 4; ++r)
        C[(row0 + r) * (long)Ncols + col] = f2bf(acc[mi][ni][r]);
    }
  }
}

// ---------------------------------------------------------------------------
// attention helper kernels (h is bf16 now)
// ---------------------------------------------------------------------------
// als/ald for conv1: one 64-lane group per (node, head); C=64
__global__ __launch_bounds__(256) void alsd1_kernel(const short* __restrict__ h,
    const float* __restrict__ a_src, const float* __restrict__ a_dst,
    float* __restrict__ als, float* __restrict__ ald) {
  const int g = (blockIdx.x * 256 + threadIdx.x) >> 6;
  const int lane = threadIdx.x & 63;
  if (g >= NNODES * 8) return;
  const int node = g >> 3, hh = g & 7;
  const float v = bf2f(h[(long)node * 512 + hh * 64 + lane]);
  float s = v * a_src[hh * 64 + lane];
  float d = v * a_dst[hh * 64 + lane];
#pragma unroll
  for (int o = 32; o > 0; o >>= 1) { s += __shfl_xor(s, o); d += __shfl_xor(d, o); }
  if (lane == 0) { als[g] = s; ald[g] = d; }
}

// als/ald for conv2: one 64-lane group per node; C=512
__global__ __launch_bounds__(256) void alsd2_kernel(const short* __restrict__ h,
    const float* __restrict__ a_src, const float* __restrict__ a_dst,
    float* __restrict__ als, float* __restrict__ ald) {
  const int g = (blockIdx.x * 256 + threadIdx.x) >> 6;
  const int lane = threadIdx.x & 63;
  if (g >= NNODES) return;
  float s = 0.f, d = 0.f;
#pragma unroll
  for (int j = 0; j < 8; ++j) {
    const int c = j * 64 + lane;
    const float v = bf2f(h[(long)g * 512 + c]);
    s += v * a_src[c];
    d += v * a_dst[c];
  }
#pragma unroll
  for (int o = 32; o > 0; o >>= 1) { s += __shfl_xor(s, o); d += __shfl_xor(d, o); }
  if (lane == 0) { als[g] = s; ald[g] = d; }
}

__global__ void deg_count_kernel(const int* __restrict__ ei, int* __restrict__ deg) {
  const int e = blockIdx.x * 256 + threadIdx.x;
  if (e >= ETOT) return;
  const int d = (e < NEDGES) ? ei[NEDGES + e] : (e - NEDGES);
  atomicAdd(&deg[d], 1);
}

// single-block exclusive scan over 20000 degrees -> off, cursor
__global__ __launch_bounds__(256) void scan_kernel(const int* __restrict__ deg,
                                                   int* __restrict__ off,
                                                   int* __restrict__ cur) {
  __shared__ int part[256];
  const int tid = threadIdx.x;
  const int chunk = (NNODES + 255) / 256;
  int start = tid * chunk;
  int end = start + chunk; if (end > NNODES) end = NNODES;
  int s = 0;
  for (int i = start; i < end; ++i) s += deg[i];
  part[tid] = s;
  __syncthreads();
  for (int d = 1; d < 256; d <<= 1) {
    const int v = (tid >= d) ? part[tid - d] : 0;
    __syncthreads();
    part[tid] += v;
    __syncthreads();
  }
  int base = part[tid] - s;   // exclusive base of this thread's chunk
  for (int i = start; i < end; ++i) { off[i] = base; cur[i] = base; base += deg[i]; }
}

__global__ void csr_fill_kernel(const int* __restrict__ ei, int* __restrict__ cur,
                                int* __restrict__ csrs) {
  const int e = blockIdx.x * 256 + threadIdx.x;
  if (e >= ETOT) return;
  const int s = (e < NEDGES) ? ei[e] : (e - NEDGES);
  const int d = (e < NEDGES) ? ei[NEDGES + e] : (e - NEDGES);
  csrs[atomicAdd(&cur[d], 1)] = s;
}

// ---------------------------------------------------------------------------
// fused per-node softmax + gather (conv1): block of 128 thr per dst node,
// thread owns 4 channels; head = (4*tid)>>6. Softmax without max-shift
// (logits bounded, shift-invariant). No atomics.
// ---------------------------------------------------------------------------
__global__ __launch_bounds__(128) void gather1_kernel(const int* __restrict__ off,
    const int* __restrict__ csrs,
    const float* __restrict__ als, const float* __restrict__ ald,
    const short* __restrict__ h1, const float* __restrict__ bias,
    short* __restrict__ ef1) {
  const int dn = blockIdx.x;
  const int tid = threadIdx.x;       // 0..127
  const int c0 = tid * 4;
  const int h = c0 >> 6;
  const int beg = off[dn];
  const int end = (dn == NNODES - 1) ? ETOT : off[dn + 1];
  const float ad = ald[dn * 8 + h];
  float sum = 0.f, a0 = 0.f, a1 = 0.f, a2 = 0.f, a3 = 0.f;
  for (int i = beg; i < end; ++i) {
    const int s = csrs[i];
    float l = als[s * 8 + h] + ad;
    l = l > 0.f ? l : NSLOPE * l;
    const float wgt = expf(l);
    sum += wgt;
    const short4 hv = *(const short4*)&h1[(long)s * 512 + c0];
    a0 += wgt * bf2f(hv.x);
    a1 += wgt * bf2f(hv.y);
    a2 += wgt * bf2f(hv.z);
    a3 += wgt * bf2f(hv.w);
  }
  const float inv = 1.f / (sum + 1e-16f);
  float r0 = a0 * inv + bias[c0];
  float r1 = a1 * inv + bias[c0 + 1];
  float r2 = a2 * inv + bias[c0 + 2];
  float r3 = a3 * inv + bias[c0 + 3];
  r0 = r0 > 0.f ? r0 : expm1f(r0);   // elu
  r1 = r1 > 0.f ? r1 : expm1f(r1);
  r2 = r2 > 0.f ? r2 : expm1f(r2);
  r3 = r3 > 0.f ? r3 : expm1f(r3);
  short4 out;
  out.x = f2bf(r0); out.y = f2bf(r1); out.z = f2bf(r2); out.w = f2bf(r3);
  *(short4*)&ef1[(long)dn * 512 + c0] = out;
}

// fused per-node softmax + gather (conv2, H=1): writes obj_feats slice (f32)
__global__ __launch_bounds__(128) void gather2_kernel(const int* __restrict__ off,
    const int* __restrict__ csrs,
    const float* __restrict__ als, const float* __restrict__ ald,
    const short* __restrict__ h2, const float* __restrict__ bias,
    float* __restrict__ dout) {
  const int dn = blockIdx.x;
  const int tid = threadIdx.x;       // 0..127
  const int c0 = tid * 4;
  const int beg = off[dn];
  const int end = (dn == NNODES - 1) ? ETOT : off[dn + 1];
  const float ad = ald[dn];
  float sum = 0.f, a0 = 0.f, a1 = 0.f, a2 = 0.f, a3 = 0.f;
  for (int i = beg; i < end; ++i) {
    const int s = csrs[i];
    float l = als[s] + ad;
    l = l > 0.f ? l : NSLOPE * l;
    const float wgt = expf(l);
    sum += wgt;
    const short4 hv = *(const short4*)&h2[(long)s * 512 + c0];
    a0 += wgt * bf2f(hv.x);
    a1 += wgt * bf2f(hv.y);
    a2 += wgt * bf2f(hv.z);
    a3 += wgt * bf2f(hv.w);
  }
  const float inv = 1.f / (sum + 1e-16f);
  float4 out;
  out.x = a0 * inv + bias[c0];
  out.y = a1 * inv + bias[c0 + 1];
  out.z = a2 * inv + bias[c0 + 2];
  out.w = a3 * inv + bias[c0 + 3];
  float* epr = dout + OUT_EPR_OFF + (long)dn * EPRW + 4096;
  *(float4*)&epr[c0] = out;
}

// ---------------------------------------------------------------------------
extern "C" void kernel_launch(void* const* d_in, const int* in_sizes, int n_in,
                              void* d_out, int out_size, void* d_ws, size_t ws_size,
                              hipStream_t stream) {
  const float* roi  = (const float*)d_in[0];
  const float* box  = (const float*)d_in[1];
  const float* emb1 = (const float*)d_in[2];
  const float* emb2 = (const float*)d_in[3];
  const float* bw1  = (const float*)d_in[4];
  const float* bb1  = (const float*)d_in[5];
  const float* bw2  = (const float*)d_in[6];
  const float* bb2  = (const float*)d_in[7];
  const float* W1   = (const float*)d_in[8];
  const float* as1  = (const float*)d_in[9];
  const float* ad1  = (const float*)d_in[10];
  const float* b1   = (const float*)d_in[11];
  const float* W2   = (const float*)d_in[12];
  const float* as2  = (const float*)d_in[13];
  const float* ad2  = (const float*)d_in[14];
  const float* b2   = (const float*)d_in[15];
  const int* labels = (const int*)d_in[16];
  const int* ei     = (const int*)d_in[17];
  float* dout = (float*)d_out;

  char* wsb = (char*)d_ws;
  size_t o = 0;
  auto alloc = [&](size_t bytes) -> void* {
    void* p = wsb + o;
    o += (bytes + 255) & ~(size_t)255;
    return p;
  };
  short* x    = (short*)alloc((size_t)MPAD * KPAD1 * 2);   // bf16 [MPAD][4448]
  short* w1t  = (short*)alloc((size_t)512 * KPAD1 * 2);    // bf16 [512][4448]
  short* h1   = (short*)alloc((size_t)MPAD * 512 * 2);     // bf16
  short* ef1  = (short*)alloc((size_t)MPAD * 512 * 2);     // bf16 [MPAD][512]
  short* w2t  = (short*)alloc((size_t)512 * 512 * 2);
  short* h2   = (short*)alloc((size_t)MPAD * 512 * 2);     // bf16
  float* als1 = (float*)alloc((size_t)NNODES * 8 * 4);
  float* ald1 = (float*)alloc((size_t)NNODES * 8 * 4);
  float* als2 = (float*)alloc((size_t)NNODES * 4);
  float* ald2 = (float*)alloc((size_t)NNODES * 4);
  int*   deg  = (int*)alloc((size_t)NNODES * 4);
  int*   offs = (int*)alloc((size_t)NNODES * 4);
  int*   cur  = (int*)alloc((size_t)NNODES * 4);
  int*   csrs = (int*)alloc((size_t)ETOT * 4);

  const int EB = (ETOT + 255) / 256;   // 1329

  hipLaunchKernelGGL(build_x_kernel, dim3(NNODES), dim3(256), 0, stream,
                     roi, box, emb1, emb2, bw1, bb1, bw2, bb2, labels, x, dout);
  hipLaunchKernelGGL(pad_zero_kernel, dim3((96 * KPAD1 + 255) / 256), dim3(256), 0, stream,
                     x, ef1, deg);
  hipLaunchKernelGGL(transpose_w_kernel, dim3(512 / 32, KPAD1 / 32), dim3(32, 8), 0, stream,
                     W1, w1t, 4424, KPAD1, 512);
  hipLaunchKernelGGL(transpose_w_kernel, dim3(512 / 32, 512 / 32), dim3(32, 8), 0, stream,
                     W2, w2t, 512, 512, 512);
  // CSR build
  hipLaunchKernelGGL(deg_count_kernel, dim3(EB), dim3(256), 0, stream, ei, deg);
  hipLaunchKernelGGL(scan_kernel, dim3(1), dim3(256), 0, stream, deg, offs, cur);
  hipLaunchKernelGGL(csr_fill_kernel, dim3(EB), dim3(256), 0, stream, ei, cur, csrs);
  // conv1
  hipLaunchKernelGGL(gemm_bt, dim3(MPAD / 128, 4), dim3(256), 0, stream,
                     x, w1t, h1, KPAD1, 512);
  hipLaunchKernelGGL(alsd1_kernel, dim3(NNODES * 8 * 64 / 256), dim3(256), 0, stream,
                     h1, as1, ad1, als1, ald1);
  hipLaunchKernelGGL(gather1_kernel, dim3(NNODES), dim3(128), 0, stream,
                     offs, csrs, als1, ald1, h1, b1, ef1);
  // conv2
  hipLaunchKernelGGL(gemm_bt, dim3(MPAD / 128, 4), dim3(256), 0, stream,
                     ef1, w2t, h2, 512, 512);
  hipLaunchKernelGGL(alsd2_kernel, dim3(NNODES * 64 / 256), dim3(256), 0, stream,
                     h2, as2, ad2, als2, ald2);
  hipLaunchKernelGGL(gather2_kernel, dim3(NNODES), dim3(128), 0, stream,
                     offs, csrs, als2, ald2, h2, b2, dout);
}

// Round 5
// 592.980 us; speedup vs baseline: 1.7547x; 1.0097x over previous
//
#include <hip/hip_runtime.h>
#include <hip/hip_bf16.h>

#define NNODES 20000
#define NEDGES 320000
#define ETOT   (NEDGES + NNODES)   // 340000, self-loops appended after edges
#define KPAD1  4448                // 4424 padded to /32
#define MPAD   20096               // 157*128
#define NCLS   151
#define EPRW   4808                // 4096 + 512 + 200
#define OUT_LAB_OFF  3020000L      // N*151
#define OUT_EPR_OFF  3040000L      // N*151 + N
#define NSLOPE 0.2f

typedef __attribute__((ext_vector_type(8))) short bf16x8;
typedef __attribute__((ext_vector_type(4))) float f32x4;

__device__ __forceinline__ short f2bf(float v) {
  union { __hip_bfloat16 b; short s; } u;
  u.b = __float2bfloat16(v);
  return u.s;
}

__device__ __forceinline__ float bf2f(short s) {
  union { float f; unsigned u; } x;
  x.u = ((unsigned)(unsigned short)s) << 16;
  return x.f;
}

__device__ __forceinline__ void gld16(const short* g, short* l) {
  __builtin_amdgcn_global_load_lds(
      (const __attribute__((address_space(1))) unsigned int*)g,
      (__attribute__((address_space(3))) unsigned int*)l, 16, 0, 0);
}

// ---------------------------------------------------------------------------
// build x (bf16, K-padded), plus obj_dists one-hot, labels, epr roi/emb2 parts
// one block (256 thr) per node. d_out is FLOAT32. Vectorized float4/short4.
// ---------------------------------------------------------------------------
__global__ __launch_bounds__(256) void build_x_kernel(
    const float* __restrict__ roi, const float* __restrict__ box,
    const float* __restrict__ emb1, const float* __restrict__ emb2,
    const float* __restrict__ bw1, const float* __restrict__ bb1,
    const float* __restrict__ bw2, const float* __restrict__ bb2,
    const int* __restrict__ labels,
    short* __restrict__ x, float* __restrict__ dout) {
  const int n = blockIdx.x;
  const int tid = threadIdx.x;
  __shared__ float hid[32];
  __shared__ float bx[9];
  if (tid < 9) bx[tid] = box[n * 9 + tid];
  __syncthreads();
  if (tid < 32) {
    float a = bb1[tid];
#pragma unroll
    for (int i = 0; i < 9; ++i) a += bx[i] * bw1[i * 32 + tid];
    hid[tid] = a > 0.f ? a : 0.f;
  }
  __syncthreads();
  const long xrow = (long)n * KPAD1;
  if (tid < 128) {
    float a = bb2[tid];
#pragma unroll
    for (int i = 0; i < 32; ++i) a += hid[i] * bw2[i * 128 + tid];
    a = a > 0.f ? a : 0.f;
    x[xrow + 4296 + tid] = f2bf(a);      // pos MLP output (x cols 4296..4423)
  }
  if (tid >= 128 && tid < 152) x[xrow + 4424 + (tid - 128)] = 0;  // K pad
  const int lab = labels[n];
  float* epr = dout + OUT_EPR_OFF + (long)n * EPRW;
#pragma unroll
  for (int j = tid * 4; j < 4096; j += 1024) {
    const float4 v = *(const float4*)&roi[(long)n * 4096 + j];
    *(float4*)&epr[j] = v;               // exact f32 copy
    short4 b;
    b.x = f2bf(v.x); b.y = f2bf(v.y); b.z = f2bf(v.z); b.w = f2bf(v.w);
    *(short4*)&x[xrow + j] = b;
  }
  if (tid < 50) {
    const int j = tid * 4;
    const float4 e1 = *(const float4*)&emb1[lab * 200 + j];
    short4 b;
    b.x = f2bf(e1.x); b.y = f2bf(e1.y); b.z = f2bf(e1.z); b.w = f2bf(e1.w);
    *(short4*)&x[xrow + 4096 + j] = b;
    *(float4*)&epr[4608 + j] = *(const float4*)&emb2[lab * 200 + j];
  }
  for (int j = tid; j < NCLS; j += 256)
    dout[(long)n * NCLS + j] = (j == lab) ? 1.f : 0.f;
  if (tid == 0) dout[OUT_LAB_OFF + n] = (float)lab;
}

// zero: x/ef1 M-pad rows, deg, als/ald accumulators
__global__ void misc_init_kernel(short* __restrict__ x, short* __restrict__ ef1,
                                 int* __restrict__ deg,
                                 float* __restrict__ als1, float* __restrict__ ald1,
                                 float* __restrict__ als2, float* __restrict__ ald2) {
  const int t = blockIdx.x * 256 + threadIdx.x;
  if (t < 96 * KPAD1) x[(long)NNODES * KPAD1 + t] = 0;
  if (t < 96 * 512)   ef1[(long)NNODES * 512 + t] = 0;
  if (t < NNODES)     deg[t] = 0;
  if (t < MPAD * 8)   { als1[t] = 0.f; ald1[t] = 0.f; }
  if (t < MPAD)       { als2[t] = 0.f; ald2[t] = 0.f; }
}

// LDS-tiled transpose: WT[n][kp] = (kp < K) ? W[kp][n] : 0  (f32 -> bf16)
// block (32,8), grid (Ncols/32, Kpad/32)
__global__ __launch_bounds__(256) void transpose_w_kernel(
    const float* __restrict__ W, short* __restrict__ WT, int K, int Kpad, int Ncols) {
  __shared__ float tile[32][33];
  const int n0 = blockIdx.x * 32;
  const int k0 = blockIdx.y * 32;
  const int tx = threadIdx.x;   // 0..31
  const int ty = threadIdx.y;   // 0..7
#pragma unroll
  for (int i = ty; i < 32; i += 8) {
    const int k = k0 + i;
    tile[i][tx] = (k < K) ? W[(long)k * Ncols + (n0 + tx)] : 0.f;
  }
  __syncthreads();
#pragma unroll
  for (int i = ty; i < 32; i += 8) {
    WT[(long)(n0 + i) * Kpad + (k0 + tx)] = f2bf(tile[tx][i]);
  }
}

// ---------------------------------------------------------------------------
// C[Mpad,Ncols] bf16 = A[Mpad,Kpad] bf16 @ BT[Ncols,Kpad]^T bf16
// 128x128 tile, BK=32, 4 waves, global_load_lds width 16 (m97 structure).
// Epilogue also accumulates als/ald (attention src/dst logits) via
// 16-lane shuffle reduce + atomicAdd — head is wave-uniform.
// ---------------------------------------------------------------------------
__global__ __launch_bounds__(256) void gemm_bt(const short* __restrict__ A,
                                               const short* __restrict__ BT,
                                               short* __restrict__ C,
                                               const float* __restrict__ aS,
                                               const float* __restrict__ aD,
                                               float* __restrict__ als,
                                               float* __restrict__ ald,
                                               int Kpad, int Ncols, int H) {
  __shared__ short As[4096];   // [128 rows][32 k]
  __shared__ short Bs[4096];   // [128 cols][32 k]
  const int tid = threadIdx.x;
  const int lane = tid & 63;
  const int w = tid >> 6;
  const int wr = w >> 1, wc = w & 1;
  const long bm = (long)blockIdx.x * 128;
  const long bn = (long)blockIdx.y * 128;

  f32x4 acc[4][4] = {};

  const short* gA0 = A + (bm + w * 32 + (lane >> 2)) * (long)Kpad + (lane & 3) * 8;
  const short* gA1 = gA0 + 16L * Kpad;
  const short* gB0 = BT + (bn + w * 32 + (lane >> 2)) * (long)Kpad + (lane & 3) * 8;
  const short* gB1 = gB0 + 16L * Kpad;
  short* lA0 = &As[w * 1024];
  short* lA1 = &As[w * 1024 + 512];
  short* lB0 = &Bs[w * 1024];
  short* lB1 = &Bs[w * 1024 + 512];

  const int ar = (wr * 64 + (lane & 15)) * 32 + (lane >> 4) * 8;
  const int br = (wc * 64 + (lane & 15)) * 32 + (lane >> 4) * 8;

  for (int k0 = 0; k0 < Kpad; k0 += 32) {
    gld16(gA0, lA0); gld16(gA1, lA1);
    gld16(gB0, lB0); gld16(gB1, lB1);
    gA0 += 32; gA1 += 32; gB0 += 32; gB1 += 32;
    asm volatile("s_waitcnt vmcnt(0)" ::: "memory");
    __syncthreads();
    bf16x8 a[4], b[4];
#pragma unroll
    for (int mi = 0; mi < 4; ++mi) a[mi] = *(const bf16x8*)&As[ar + mi * 512];
#pragma unroll
    for (int ni = 0; ni < 4; ++ni) b[ni] = *(const bf16x8*)&Bs[br + ni * 512];
#pragma unroll
    for (int mi = 0; mi < 4; ++mi)
#pragma unroll
      for (int ni = 0; ni < 4; ++ni)
        acc[mi][ni] = __builtin_amdgcn_mfma_f32_16x16x32_bf16(a[mi], b[ni], acc[mi][ni], 0, 0, 0);
    __syncthreads();
  }

  // C-write (bf16)
#pragma unroll
  for (int mi = 0; mi < 4; ++mi) {
#pragma unroll
    for (int ni = 0; ni < 4; ++ni) {
      const long row0 = bm + wr * 64 + mi * 16 + (lane >> 4) * 4;
      const long col  = bn + wc * 64 + ni * 16 + (lane & 15);
#pragma unroll
      for (int r = 0; r < 4; ++r)
        C[(row0 + r) * (long)Ncols + col] = f2bf(acc[mi][ni][r]);
    }
  }

  // fused als/ald: this wave's 64 cols lie within one head (H=8) or head 0 (H=1)
  const int colb = (int)bn + wc * 64 + (lane & 15);
  float asv[4], adv[4];
#pragma unroll
  for (int ni = 0; ni < 4; ++ni) {
    asv[ni] = aS[colb + ni * 16];
    adv[ni] = aD[colb + ni * 16];
  }
  const int head = (H == 8) ? (((int)bn >> 6) + wc) : 0;
#pragma unroll
  for (int mi = 0; mi < 4; ++mi) {
#pragma unroll
    for (int r = 0; r < 4; ++r) {
      float s = 0.f, d = 0.f;
#pragma unroll
      for (int ni = 0; ni < 4; ++ni) {
        const float v = acc[mi][ni][r];
        s += v * asv[ni];
        d += v * adv[ni];
      }
#pragma unroll
      for (int o = 1; o < 16; o <<= 1) {
        s += __shfl_xor(s, o);
        d += __shfl_xor(d, o);
      }
      if ((lane & 15) == 0) {
        const long row = bm + wr * 64 + mi * 16 + (lane >> 4) * 4 + r;
        atomicAdd(&als[row * H + head], s);
        atomicAdd(&ald[row * H + head], d);
      }
    }
  }
}

// ---------------------------------------------------------------------------
// CSR build
// ---------------------------------------------------------------------------
__global__ void deg_count_kernel(const int* __restrict__ ei, int* __restrict__ deg) {
  const int e = blockIdx.x * 256 + threadIdx.x;
  if (e >= ETOT) return;
  const int d = (e < NEDGES) ? ei[NEDGES + e] : (e - NEDGES);
  atomicAdd(&deg[d], 1);
}

// single-block exclusive scan over 20000 degrees -> off, cursor
__global__ __launch_bounds__(256) void scan_kernel(const int* __restrict__ deg,
                                                   int* __restrict__ off,
                                                   int* __restrict__ cur) {
  __shared__ int part[256];
  const int tid = threadIdx.x;
  const int chunk = (NNODES + 255) / 256;
  int start = tid * chunk;
  int end = start + chunk; if (end > NNODES) end = NNODES;
  int s = 0;
  for (int i = start; i < end; ++i) s += deg[i];
  part[tid] = s;
  __syncthreads();
  for (int d = 1; d < 256; d <<= 1) {
    const int v = (tid >= d) ? part[tid - d] : 0;
    __syncthreads();
    part[tid] += v;
    __syncthreads();
  }
  int base = part[tid] - s;   // exclusive base of this thread's chunk
  for (int i = start; i < end; ++i) { off[i] = base; cur[i] = base; base += deg[i]; }
}

__global__ void csr_fill_kernel(const int* __restrict__ ei, int* __restrict__ cur,
                                int* __restrict__ csrs) {
  const int e = blockIdx.x * 256 + threadIdx.x;
  if (e >= ETOT) return;
  const int s = (e < NEDGES) ? ei[e] : (e - NEDGES);
  const int d = (e < NEDGES) ? ei[NEDGES + e] : (e - NEDGES);
  csrs[atomicAdd(&cur[d], 1)] = s;
}

// ---------------------------------------------------------------------------
// fused per-node softmax + gather (conv1): one 64-lane wave per dst node,
// 4 nodes per 256-thr block; lane owns 8 channels (16B bf16x8 loads).
// head = lane>>3. Softmax without max-shift (logits bounded). No atomics.
// ---------------------------------------------------------------------------
__global__ __launch_bounds__(256) void gather1_kernel(const int* __restrict__ off,
    const int* __restrict__ csrs,
    const float* __restrict__ als, const float* __restrict__ ald,
    const short* __restrict__ h1, const float* __restrict__ bias,
    short* __restrict__ ef1) {
  const int dn = blockIdx.x * 4 + (threadIdx.x >> 6);
  const int lane = threadIdx.x & 63;
  const int c0 = lane * 8;
  const int head = lane >> 3;
  const int beg = off[dn];
  const int end = (dn == NNODES - 1) ? ETOT : off[dn + 1];
  const float ad = ald[dn * 8 + head];
  float sum = 0.f;
  float acc[8] = {};
  for (int i = beg; i < end; ++i) {
    const int s = csrs[i];
    float l = als[s * 8 + head] + ad;
    l = l > 0.f ? l : NSLOPE * l;
    const float wgt = expf(l);
    sum += wgt;
    const bf16x8 hv = *(const bf16x8*)&h1[(long)s * 512 + c0];
#pragma unroll
    for (int j = 0; j < 8; ++j) acc[j] += wgt * bf2f(hv[j]);
  }
  const float inv = 1.f / (sum + 1e-16f);
  bf16x8 outv;
#pragma unroll
  for (int j = 0; j < 8; ++j) {
    float r = acc[j] * inv + bias[c0 + j];
    r = r > 0.f ? r : expm1f(r);   // elu
    outv[j] = f2bf(r);
  }
  *(bf16x8*)&ef1[(long)dn * 512 + c0] = outv;
}

// fused per-node softmax + gather (conv2, H=1): writes obj_feats slice (f32)
__global__ __launch_bounds__(256) void gather2_kernel(const int* __restrict__ off,
    const int* __restrict__ csrs,
    const float* __restrict__ als, const float* __restrict__ ald,
    const short* __restrict__ h2, const float* __restrict__ bias,
    float* __restrict__ dout) {
  const int dn = blockIdx.x * 4 + (threadIdx.x >> 6);
  const int lane = threadIdx.x & 63;
  const int c0 = lane * 8;
  const int beg = off[dn];
  const int end = (dn == NNODES - 1) ? ETOT : off[dn + 1];
  const float ad = ald[dn];
  float sum = 0.f;
  float acc[8] = {};
  for (int i = beg; i < end; ++i) {
    const int s = csrs[i];
    float l = als[s] + ad;
    l = l > 0.f ? l : NSLOPE * l;
    const float wgt = expf(l);
    sum += wgt;
    const bf16x8 hv = *(const bf16x8*)&h2[(long)s * 512 + c0];
#pragma unroll
    for (int j = 0; j < 8; ++j) acc[j] += wgt * bf2f(hv[j]);
  }
  const float inv = 1.f / (sum + 1e-16f);
  float* epr = dout + OUT_EPR_OFF + (long)dn * EPRW + 4096;
  float4 o0, o1;
  o0.x = acc[0] * inv + bias[c0 + 0];
  o0.y = acc[1] * inv + bias[c0 + 1];
  o0.z = acc[2] * inv + bias[c0 + 2];
  o0.w = acc[3] * inv + bias[c0 + 3];
  o1.x = acc[4] * inv + bias[c0 + 4];
  o1.y = acc[5] * inv + bias[c0 + 5];
  o1.z = acc[6] * inv + bias[c0 + 6];
  o1.w = acc[7] * inv + bias[c0 + 7];
  *(float4*)&epr[c0]     = o0;
  *(float4*)&epr[c0 + 4] = o1;
}

// ---------------------------------------------------------------------------
extern "C" void kernel_launch(void* const* d_in, const int* in_sizes, int n_in,
                              void* d_out, int out_size, void* d_ws, size_t ws_size,
                              hipStream_t stream) {
  const float* roi  = (const float*)d_in[0];
  const float* box  = (const float*)d_in[1];
  const float* emb1 = (const float*)d_in[2];
  const float* emb2 = (const float*)d_in[3];
  const float* bw1  = (const float*)d_in[4];
  const float* bb1  = (const float*)d_in[5];
  const float* bw2  = (const float*)d_in[6];
  const float* bb2  = (const float*)d_in[7];
  const float* W1   = (const float*)d_in[8];
  const float* as1  = (const float*)d_in[9];
  const float* ad1  = (const float*)d_in[10];
  const float* b1   = (const float*)d_in[11];
  const float* W2   = (const float*)d_in[12];
  const float* as2  = (const float*)d_in[13];
  const float* ad2  = (const float*)d_in[14];
  const float* b2   = (const float*)d_in[15];
  const int* labels = (const int*)d_in[16];
  const int* ei     = (const int*)d_in[17];
  float* dout = (float*)d_out;

  char* wsb = (char*)d_ws;
  size_t o = 0;
  auto alloc = [&](size_t bytes) -> void* {
    void* p = wsb + o;
    o += (bytes + 255) & ~(size_t)255;
    return p;
  };
  short* x    = (short*)alloc((size_t)MPAD * KPAD1 * 2);   // bf16 [MPAD][4448]
  short* w1t  = (short*)alloc((size_t)512 * KPAD1 * 2);    // bf16 [512][4448]
  short* h1   = (short*)alloc((size_t)MPAD * 512 * 2);     // bf16
  short* ef1  = (short*)alloc((size_t)MPAD * 512 * 2);     // bf16 [MPAD][512]
  short* w2t  = (short*)alloc((size_t)512 * 512 * 2);
  short* h2   = (short*)alloc((size_t)MPAD * 512 * 2);     // bf16
  float* als1 = (float*)alloc((size_t)MPAD * 8 * 4);
  float* ald1 = (float*)alloc((size_t)MPAD * 8 * 4);
  float* als2 = (float*)alloc((size_t)MPAD * 4);
  float* ald2 = (float*)alloc((size_t)MPAD * 4);
  int*   deg  = (int*)alloc((size_t)NNODES * 4);
  int*   offs = (int*)alloc((size_t)NNODES * 4);
  int*   cur  = (int*)alloc((size_t)NNODES * 4);
  int*   csrs = (int*)alloc((size_t)ETOT * 4);

  const int EB = (ETOT + 255) / 256;   // 1329

  hipLaunchKernelGGL(build_x_kernel, dim3(NNODES), dim3(256), 0, stream,
                     roi, box, emb1, emb2, bw1, bb1, bw2, bb2, labels, x, dout);
  hipLaunchKernelGGL(misc_init_kernel, dim3((96 * KPAD1 + 255) / 256), dim3(256), 0, stream,
                     x, ef1, deg, als1, ald1, als2, ald2);
  hipLaunchKernelGGL(transpose_w_kernel, dim3(512 / 32, KPAD1 / 32), dim3(32, 8), 0, stream,
                     W1, w1t, 4424, KPAD1, 512);
  hipLaunchKernelGGL(transpose_w_kernel, dim3(512 / 32, 512 / 32), dim3(32, 8), 0, stream,
                     W2, w2t, 512, 512, 512);
  // CSR build
  hipLaunchKernelGGL(deg_count_kernel, dim3(EB), dim3(256), 0, stream, ei, deg);
  hipLaunchKernelGGL(scan_kernel, dim3(1), dim3(256), 0, stream, deg, offs, cur);
  hipLaunchKernelGGL(csr_fill_kernel, dim3(EB), dim3(256), 0, stream, ei, cur, csrs);
  // conv1 (GEMM + fused als/ald)
  hipLaunchKernelGGL(gemm_bt, dim3(MPAD / 128, 4), dim3(256), 0, stream,
                     x, w1t, h1, as1, ad1, als1, ald1, KPAD1, 512, 8);
  hipLaunchKernelGGL(gather1_kernel, dim3(NNODES / 4), dim3(256), 0, stream,
                     offs, csrs, als1, ald1, h1, b1, ef1);
  // conv2 (GEMM + fused als/ald)
  hipLaunchKernelGGL(gemm_bt, dim3(MPAD / 128, 4), dim3(256), 0, stream,
                     ef1, w2t, h2, as2, ad2, als2, ald2, 512, 512, 1);
  hipLaunchKernelGGL(gather2_kernel, dim3(NNODES / 4), dim3(256), 0, stream,
                     offs, csrs, als2, ald2, h2, b2, dout);
}